// Round 7
// baseline (186.397 us; speedup 1.0000x reference)
//
#include <hip/hip_runtime.h>
#include <hip/hip_bf16.h>

typedef unsigned short u16;
typedef unsigned int u32;
typedef short s16x8 __attribute__((ext_vector_type(8)));
typedef float f32x4 __attribute__((ext_vector_type(4)));

// fp32 -> bf16 round-to-nearest-even
__device__ inline u16 f2bf(float f) {
  union { float f; unsigned int u; } v; v.f = f;
  unsigned int r = v.u + 0x7fffu + ((v.u >> 16) & 1u);
  return (u16)(r >> 16);
}

// async 16B global -> LDS DMA (lane i of the wave lands at ldsbase + i*16)
__device__ __forceinline__ void g2lds16(const u16* g, u16* l) {
  __builtin_amdgcn_global_load_lds((const __attribute__((address_space(1))) void*)g,
                                   (__attribute__((address_space(3))) void*)l, 16, 0, 0);
}

// ---------------------------------------------------------------- prep: cast x + transpose-cast W (one launch)
__global__ __launch_bounds__(256) void prep_kernel(const float* __restrict__ x,
                                                   const float* __restrict__ Wq,
                                                   const float* __restrict__ Wk,
                                                   const float* __restrict__ Wv,
                                                   u16* __restrict__ xb, u16* __restrict__ wt) {
  __shared__ float tile[64][65];
  int bid = blockIdx.x;
  if (bid < 1024) {
    int i = (bid * 256 + threadIdx.x) * 8;
    float4 a = *(const float4*)(x + i);
    float4 b = *(const float4*)(x + i + 4);
    s16x8 o;
    o[0] = (short)f2bf(a.x); o[1] = (short)f2bf(a.y);
    o[2] = (short)f2bf(a.z); o[3] = (short)f2bf(a.w);
    o[4] = (short)f2bf(b.x); o[5] = (short)f2bf(b.y);
    o[6] = (short)f2bf(b.z); o[7] = (short)f2bf(b.w);
    *(s16x8*)(xb + i) = o;
    return;
  }
  int t = bid - 1024;
  const float* src; int C, rowoff, j0, k0;
  if (t < 256) {
    src = (t < 128) ? Wq : Wk;
    C = 1024; rowoff = (t < 128) ? 0 : 1024;
    int tt = t & 127;
    j0 = (tt & 15) * 64; k0 = (tt >> 4) * 64;
  } else {
    src = Wv; C = 512; rowoff = 2048;
    int tt = t - 256;
    j0 = (tt & 7) * 64; k0 = (tt >> 3) * 64;
  }
  int tx = threadIdx.x % 64, ty4 = threadIdx.x / 64;
#pragma unroll
  for (int p = 0; p < 16; ++p) {
    int r = p * 4 + ty4;
    tile[r][tx] = src[(size_t)(k0 + r) * C + j0 + tx];
  }
  __syncthreads();
#pragma unroll
  for (int p = 0; p < 16; ++p) {
    int r = p * 4 + ty4;
    wt[(size_t)(rowoff + j0 + r) * 512 + k0 + tx] = f2bf(tile[tx][r]);
  }
}

// ---------------------------------------------------------------- fused QKV projection GEMM (unchanged)
__global__ __launch_bounds__(256, 3) void gemm_qkv(const u16* __restrict__ xb, const u16* __restrict__ wt,
                                                   const float* __restrict__ bq, const float* __restrict__ bk,
                                                   const float* __restrict__ bv,
                                                   u16* __restrict__ qa, u16* __restrict__ ka,
                                                   u16* __restrict__ va) {
  __shared__ __align__(16) u16 As[128 * 64];
  __shared__ __align__(16) u16 Bs[128 * 64];
  int m0 = blockIdx.x * 128, j0 = blockIdx.y * 128;
  int tid = threadIdx.x;
  int w = tid >> 6, lane = tid & 63, quad = lane >> 4, l16 = lane & 15;
  int wr = (w >> 1) * 64, wc = (w & 1) * 64;

  int srow[4], scol[4], sbase[4];
#pragma unroll
  for (int it = 0; it < 4; ++it) {
    int s = it * 256 + tid;
    srow[it] = s >> 3;
    scol[it] = (s & 7) ^ ((s >> 3) & 7);
    sbase[it] = (s & ~63) * 8;
  }

  f32x4 acc[4][4];
#pragma unroll
  for (int i = 0; i < 4; ++i)
#pragma unroll
    for (int j = 0; j < 4; ++j)
#pragma unroll
      for (int r = 0; r < 4; ++r) acc[i][j][r] = 0.f;

  for (int kk = 0; kk < 8; ++kk) {
    int k0 = kk * 64;
    __syncthreads();
#pragma unroll
    for (int it = 0; it < 4; ++it) {
      g2lds16(xb + (size_t)(m0 + srow[it]) * 512 + k0 + scol[it] * 8, &As[sbase[it]]);
      g2lds16(wt + (size_t)(j0 + srow[it]) * 512 + k0 + scol[it] * 8, &Bs[sbase[it]]);
    }
    __syncthreads();
#pragma unroll
    for (int kb = 0; kb < 2; ++kb) {
      s16x8 af[4], bfr[4];
#pragma unroll
      for (int rb = 0; rb < 4; ++rb) {
        int row = wr + rb * 16 + l16;
        af[rb] = *(const s16x8*)(&As[row * 64 + (((kb * 4 + quad) ^ (row & 7)) * 8)]);
      }
#pragma unroll
      for (int cb = 0; cb < 4; ++cb) {
        int row = wc + cb * 16 + l16;
        bfr[cb] = *(const s16x8*)(&Bs[row * 64 + (((kb * 4 + quad) ^ (row & 7)) * 8)]);
      }
#pragma unroll
      for (int rb = 0; rb < 4; ++rb)
#pragma unroll
        for (int cb = 0; cb < 4; ++cb)
          acc[rb][cb] = __builtin_amdgcn_mfma_f32_16x16x32_bf16(af[rb], bfr[cb], acc[rb][cb], 0, 0, 0);
    }
  }

#pragma unroll
  for (int cb = 0; cb < 4; ++cb) {
    int j = j0 + wc + cb * 16 + l16;
    float bias = (j < 1024) ? bq[j] : (j < 2048) ? bk[j - 1024] : bv[j - 2048];
#pragma unroll
    for (int rb = 0; rb < 4; ++rb) {
#pragma unroll
      for (int r = 0; r < 4; ++r) {
        int m = m0 + wr + rb * 16 + quad * 4 + r;
        int bidx = m >> 10, n = m & 1023;
        u16 o = f2bf(acc[rb][cb][r] + bias);
        if (j < 1024) {
          int h = j >> 7, r2 = j & 127;
          qa[((size_t)((bidx * 8 + h) * 1024 + n)) * 128 + r2] = o;
        } else if (j < 2048) {
          int jj = j - 1024, h = jj >> 7, r2 = jj & 127;
          ka[((size_t)((bidx * 8 + h) * 1024 + n)) * 128 + r2] = o;
        } else {                              // v transposed: [b][h][d][n]
          int jj = j - 2048, h = jj >> 6, d = jj & 63;
          va[((size_t)((bidx * 8 + h) * 64 + d)) * 1024 + n] = o;
        }
      }
    }
  }
}

// ---------------------------------------------------------------- differential attention v6
// Barrier-free main loop: MFMA A-fragments are read DIRECTLY from global (ka's [key][feat] and
// va's [d][n] layouts are exactly the A-frag lane maps -> 16B dwordx4 loads, L2-resident).
// No LDS staging, no per-tile __syncthreads; waves fully independent until the epilogue combine.
// S^T = mfma(K,Q); P^T via shfl-transpose; O^T = mfma(V^T,P^T); l accumulated in VALU.
__global__ __launch_bounds__(256, 3) void attn_kernel(const u16* __restrict__ qa, const u16* __restrict__ ka,
                                                      const u16* __restrict__ va, float* __restrict__ out) {
  __shared__ float Ex[2 * 64 * 35];   // 17920 B: epilogue combine only
  int bh = blockIdx.x, b = bh >> 3, h = bh & 7;
  int q0 = blockIdx.y * 32;
  int tid = threadIdx.x, w = tid >> 6, lane = tid & 63, quad = lane >> 4, l16 = lane & 15;
  int kh = w >> 1;                // key-half (sequence half) this wave reduces over
  int qr = q0 + (w & 1) * 16;

  const u16* kb0 = ka + (size_t)bh * 1024 * 128 + (size_t)kh * 512 * 128;
  const u16* vb0 = va + (size_t)bh * 64 * 1024 + kh * 512;

  // q fragments: B-operand [k=feat][n=q-row]
  const u16* qrow = qa + (size_t)(bh * 1024 + qr + l16) * 128;
  s16x8 qf[2][2];
  qf[0][0] = *(const s16x8*)(qrow + quad * 8);
  qf[0][1] = *(const s16x8*)(qrow + 32 + quad * 8);
  qf[1][0] = *(const s16x8*)(qrow + 64 + quad * 8);
  qf[1][1] = *(const s16x8*)(qrow + 96 + quad * 8);

  f32x4 O1[4], O2[4];            // O^T: row = d (quad*4+r), col = q-row (l16)
#pragma unroll
  for (int i = 0; i < 4; ++i)
#pragma unroll
    for (int r = 0; r < 4; ++r) { O1[i][r] = 0.f; O2[i][r] = 0.f; }
  float lacc[2] = {0.f, 0.f};    // softmax denominators (partial)

  int srcLo = (quad & 1) * 32 + l16;    // shfl-transpose sources
  int srcHi = srcLo + 16;
  bool hiSel = quad >= 2;

#pragma unroll 2
  for (int kt = 0; kt < 16; ++kt) {
    const u16* ktk = kb0 + kt * 32 * 128;
    const u16* ktv = vb0 + kt * 32;

    // V^T A-frags direct from global: [m=d=ct*16+l16][k=key=quad*8+j]
    s16x8 vf[4];
#pragma unroll
    for (int ct = 0; ct < 4; ++ct)
      vf[ct] = *(const s16x8*)(ktv + (size_t)(ct * 16 + l16) * 1024 + quad * 8);

#pragma unroll
    for (int hh = 0; hh < 2; ++hh) {
      // S^T = K·Q^T; K A-frags direct from global: [m=key=nt*16+l16][k=feat=kb*32+quad*8]
      u32 pk[2][2];
#pragma unroll
      for (int nt = 0; nt < 2; ++nt) {
        f32x4 sv; sv[0] = sv[1] = sv[2] = sv[3] = 0.f;
#pragma unroll
        for (int kbi = 0; kbi < 2; ++kbi) {
          s16x8 kf = *(const s16x8*)(ktk + (size_t)(nt * 16 + l16) * 128 + hh * 64 + kbi * 32 + quad * 8);
          sv = __builtin_amdgcn_mfma_f32_16x16x32_bf16(kf, qf[hh][kbi], sv, 0, 0, 0);
        }
        u32 ue[4];
#pragma unroll
        for (int r = 0; r < 4; ++r) {
          float e = __expf(sv[r] * 0.125f);
          ue[r] = __float_as_uint(e);
          lacc[hh] += __uint_as_float(ue[r] & 0xffff0000u);  // sum of truncated values
        }
        pk[nt][0] = (ue[0] >> 16) | (ue[1] & 0xffff0000u);
        pk[nt][1] = (ue[2] >> 16) | (ue[3] & 0xffff0000u);
      }
      // P^T B-frag via cross-lane transpose
      u32 a0 = __shfl(pk[0][0], srcLo), b0 = __shfl(pk[1][0], srcLo);
      u32 a1 = __shfl(pk[0][1], srcLo), b1 = __shfl(pk[1][1], srcLo);
      u32 a2 = __shfl(pk[0][0], srcHi), b2 = __shfl(pk[1][0], srcHi);
      u32 a3 = __shfl(pk[0][1], srcHi), b3 = __shfl(pk[1][1], srcHi);
      union { u32 wv[4]; s16x8 frag; } pu;
      pu.wv[0] = hiSel ? b0 : a0;
      pu.wv[1] = hiSel ? b1 : a1;
      pu.wv[2] = hiSel ? b2 : a2;
      pu.wv[3] = hiSel ? b3 : a3;
      if (hh == 0) {
#pragma unroll
        for (int ct = 0; ct < 4; ++ct)
          O1[ct] = __builtin_amdgcn_mfma_f32_16x16x32_bf16(vf[ct], pu.frag, O1[ct], 0, 0, 0);
      } else {
#pragma unroll
        for (int ct = 0; ct < 4; ++ct)
          O2[ct] = __builtin_amdgcn_mfma_f32_16x16x32_bf16(vf[ct], pu.frag, O2[ct], 0, 0, 0);
      }
    }
  }

  // ---- combine key-halves through LDS (waves 2,3 -> waves 0,1); stride 35 = conflict-free ----
  if (w >= 2) {
    int base = ((w - 2) * 64 + lane) * 35;
#pragma unroll
    for (int ct = 0; ct < 4; ++ct)
#pragma unroll
      for (int r = 0; r < 4; ++r) {
        Ex[base + ct * 4 + r] = O1[ct][r];
        Ex[base + 16 + ct * 4 + r] = O2[ct][r];
      }
    Ex[base + 32] = lacc[0];
    Ex[base + 33] = lacc[1];
  }
  __syncthreads();
  if (w < 2) {
    int base = (w * 64 + lane) * 35;
#pragma unroll
    for (int ct = 0; ct < 4; ++ct)
#pragma unroll
      for (int r = 0; r < 4; ++r) {
        O1[ct][r] += Ex[base + ct * 4 + r];
        O2[ct][r] += Ex[base + 16 + ct * 4 + r];
      }
    float l1 = lacc[0] + Ex[base + 32];
    float l2 = lacc[1] + Ex[base + 33];
    l1 += __shfl_xor(l1, 16); l1 += __shfl_xor(l1, 32);
    l2 += __shfl_xor(l2, 16); l2 += __shfl_xor(l2, 32);
    float inv1 = 1.0f / l1, inv2 = 1.0f / l2;
    float* orow = out + (size_t)(b * 1024 + qr + l16) * 512 + h * 64;
#pragma unroll
    for (int ct = 0; ct < 4; ++ct) {
      float4 v;
      v.x = O1[ct][0] * inv1 - 0.5f * O2[ct][0] * inv2;
      v.y = O1[ct][1] * inv1 - 0.5f * O2[ct][1] * inv2;
      v.z = O1[ct][2] * inv1 - 0.5f * O2[ct][2] * inv2;
      v.w = O1[ct][3] * inv1 - 0.5f * O2[ct][3] * inv2;
      *(float4*)(orow + ct * 16 + quad * 4) = v;
    }
  }
}

// ---------------------------------------------------------------- launcher
extern "C" void kernel_launch(void* const* d_in, const int* in_sizes, int n_in,
                              void* d_out, int out_size, void* d_ws, size_t ws_size,
                              hipStream_t stream) {
  (void)in_sizes; (void)n_in; (void)out_size; (void)ws_size;
  const float* x  = (const float*)d_in[0];
  const float* Wq = (const float*)d_in[1];
  const float* bq = (const float*)d_in[2];
  const float* Wk = (const float*)d_in[3];
  const float* bk = (const float*)d_in[4];
  const float* Wv = (const float*)d_in[5];
  const float* bv = (const float*)d_in[6];
  float* out = (float*)d_out;

  char* ws = (char*)d_ws;
  u16* xb = (u16*)(ws);                    // 4096*512*2   = 4 MiB
  u16* wt = (u16*)(ws + 4194304);          // 2560*512*2   = 2.5 MiB
  u16* qa = (u16*)(ws + 6815744);          // 4*8*1024*128*2 = 8 MiB
  u16* ka = (u16*)(ws + 15204352);         // 8 MiB
  u16* va = (u16*)(ws + 23592960);         // 4*8*64*1024*2 = 4 MiB

  prep_kernel<<<1344, 256, 0, stream>>>(x, Wq, Wk, Wv, xb, wt);
  gemm_qkv<<<dim3(32, 20), 256, 0, stream>>>(xb, wt, bq, bk, bv, qa, ka, va);
  attn_kernel<<<dim3(32, 32), 256, 0, stream>>>(qa, ka, va, out);
}